// Round 5
// baseline (297.720 us; speedup 1.0000x reference)
//
#include <hip/hip_runtime.h>
#include <math.h>

#define HWSZ 65536
#define SDIM 2048
#define NCHUNK 64
#define CHUNKSZ 32
#define INV_TAU 14.285714285714286f
#define C_L2E 20.609929155482418f   // (1/tau) * log2(e)
#define EPSN 1e-7f

// ---------------- Kernel A: gather-diff -> MLP -> L2 normalize ----------------
// One wave per (which, b, center). LDS laid out for b128 access.
__global__ __launch_bounds__(256) void feat_kernel(
    const float* __restrict__ f_q, const float* __restrict__ f_k,
    const float* __restrict__ W0, const float* __restrict__ b0,
    const float* __restrict__ W1, const float* __restrict__ b1,
    const int* __restrict__ c_ids, const int* __restrict__ n_ids,
    float* __restrict__ Fq, float* __restrict__ Fk)
{
    __shared__ float sd[4][64][12];
    __shared__ float sh[4][8][68];
    const int w    = threadIdx.x >> 6;
    const int lane = threadIdx.x & 63;
    const int row  = blockIdx.x * 4 + w;       // 0..4095
    const int which = row >> 11;               // 0 = f_q, 1 = f_k
    const int r = row & 2047;
    const int b = r >> 8;
    const int cidx = r & 255;                  // center index

    const float* feat = which ? f_k : f_q;
    const int cid = c_ids[cidx];               // wave-uniform -> scalar loads
    const float* base = feat + ((size_t)(b * 64 + lane)) * HWSZ;  // lane = channel
    const float cval = base[cid];
    float4 d0, d1;
    d0.x = cval - base[n_ids[cidx          ]];
    d0.y = cval - base[n_ids[cidx + 256 * 1]];
    d0.z = cval - base[n_ids[cidx + 256 * 2]];
    d0.w = cval - base[n_ids[cidx + 256 * 3]];
    d1.x = cval - base[n_ids[cidx + 256 * 4]];
    d1.y = cval - base[n_ids[cidx + 256 * 5]];
    d1.z = cval - base[n_ids[cidx + 256 * 6]];
    d1.w = cval - base[n_ids[cidx + 256 * 7]];
    *(float4*)&sd[w][lane][0] = d0;
    *(float4*)&sd[w][lane][4] = d1;
    __syncthreads();

    // layer 1: lane = j; 8 samples per wave, broadcast b128 reads of d
    float acc[8];
    const float bias0 = b0[lane];
    #pragma unroll
    for (int k = 0; k < 8; ++k) acc[k] = bias0;
    #pragma unroll 8
    for (int c = 0; c < 64; ++c) {
        const float w0 = W0[c * 64 + lane];
        const float4 a = *(const float4*)&sd[w][c][0];
        const float4 e = *(const float4*)&sd[w][c][4];
        acc[0] = fmaf(a.x, w0, acc[0]);
        acc[1] = fmaf(a.y, w0, acc[1]);
        acc[2] = fmaf(a.z, w0, acc[2]);
        acc[3] = fmaf(a.w, w0, acc[3]);
        acc[4] = fmaf(e.x, w0, acc[4]);
        acc[5] = fmaf(e.y, w0, acc[5]);
        acc[6] = fmaf(e.z, w0, acc[6]);
        acc[7] = fmaf(e.w, w0, acc[7]);
    }
    #pragma unroll
    for (int k = 0; k < 8; ++k) sh[w][k][lane] = fmaxf(acc[k], 0.0f);
    __syncthreads();

    // layer 2: lane = k0*16 + i; two passes; float4 broadcast reads of h
    const int i  = lane & 15;
    const int k0 = lane >> 4;
    float* F = which ? Fk : Fq;
    #pragma unroll
    for (int p = 0; p < 2; ++p) {
        const int k = p * 4 + k0;
        float o = b1[i];
        #pragma unroll
        for (int j4 = 0; j4 < 16; ++j4) {
            const float4 h4 = *(const float4*)&sh[w][k][j4 * 4];
            o = fmaf(h4.x, W1[(j4 * 4 + 0) * 16 + i], o);
            o = fmaf(h4.y, W1[(j4 * 4 + 1) * 16 + i], o);
            o = fmaf(h4.z, W1[(j4 * 4 + 2) * 16 + i], o);
            o = fmaf(h4.w, W1[(j4 * 4 + 3) * 16 + i], o);
        }
        float s2 = o * o;
        s2 += __shfl_xor(s2, 1, 16);
        s2 += __shfl_xor(s2, 2, 16);
        s2 += __shfl_xor(s2, 4, 16);
        s2 += __shfl_xor(s2, 8, 16);
        const float val = o / (sqrtf(s2) + EPSN);
        const int s = cidx + 256 * k;
        F[((size_t)(b * SDIM + s)) * 16 + i] = val;
    }
}

__device__ __forceinline__ float dot16(const float4 qa, const float4 qb,
                                       const float4 qc, const float4 qd,
                                       const float* __restrict__ krow)
{
    const float4* k4 = (const float4*)krow;
    const float4 ka = k4[0], kb = k4[1], kc = k4[2], kd = k4[3];
    float d = qa.x * ka.x;
    d = fmaf(qa.y, ka.y, d); d = fmaf(qa.z, ka.z, d); d = fmaf(qa.w, ka.w, d);
    d = fmaf(qb.x, kb.x, d); d = fmaf(qb.y, kb.y, d); d = fmaf(qb.z, kb.z, d); d = fmaf(qb.w, kb.w, d);
    d = fmaf(qc.x, kc.x, d); d = fmaf(qc.y, kc.y, d); d = fmaf(qc.z, kc.z, d); d = fmaf(qc.w, kc.w, d);
    d = fmaf(qd.x, kd.x, d); d = fmaf(qd.y, kd.y, d); d = fmaf(qd.z, kd.z, d); d = fmaf(qd.w, kd.w, d);
    return d;
}

// ---------------- Kernel B: Gram row partial logsumexp sums ----------------
// grid = (4, NCHUNK, B) = 2048 blocks. Each thread owns TWO s rows (s0, s0+1024)
// so each Fk-row load feeds 2 dots. exp folded to a single v_exp_f32 (base 2).
__global__ __launch_bounds__(256) void gram_kernel(
    const float* __restrict__ Fq, const float* __restrict__ Fk,
    float* __restrict__ partial, float* __restrict__ diag)
{
    const int s0    = blockIdx.x * 256 + threadIdx.x;   // 0..1023
    const int s1    = s0 + 1024;
    const int chunk = blockIdx.y;
    const int b     = blockIdx.z;

    const float4* q04 = (const float4*)(Fq + ((size_t)(b * SDIM + s0)) * 16);
    const float4 q0a = q04[0], q0b = q04[1], q0c = q04[2], q0d = q04[3];
    const float4* q14 = (const float4*)(Fq + ((size_t)(b * SDIM + s1)) * 16);
    const float4 q1a = q14[0], q1b = q14[1], q1c = q14[2], q1d = q14[3];
    const float* fk = Fk + (size_t)b * SDIM * 16;

    float sum0 = 0.0f, sum1 = 0.0f;
    const int t0 = chunk * CHUNKSZ;
    #pragma unroll 2
    for (int t = t0; t < t0 + CHUNKSZ; ++t) {
        const float4* k4 = (const float4*)(fk + (size_t)t * 16);
        const float4 ka = k4[0], kb = k4[1], kc = k4[2], kd = k4[3];
        float da = q0a.x * ka.x, db = q1a.x * ka.x;
        da = fmaf(q0a.y, ka.y, da); db = fmaf(q1a.y, ka.y, db);
        da = fmaf(q0a.z, ka.z, da); db = fmaf(q1a.z, ka.z, db);
        da = fmaf(q0a.w, ka.w, da); db = fmaf(q1a.w, ka.w, db);
        da = fmaf(q0b.x, kb.x, da); db = fmaf(q1b.x, kb.x, db);
        da = fmaf(q0b.y, kb.y, da); db = fmaf(q1b.y, kb.y, db);
        da = fmaf(q0b.z, kb.z, da); db = fmaf(q1b.z, kb.z, db);
        da = fmaf(q0b.w, kb.w, da); db = fmaf(q1b.w, kb.w, db);
        da = fmaf(q0c.x, kc.x, da); db = fmaf(q1c.x, kc.x, db);
        da = fmaf(q0c.y, kc.y, da); db = fmaf(q1c.y, kc.y, db);
        da = fmaf(q0c.z, kc.z, da); db = fmaf(q1c.z, kc.z, db);
        da = fmaf(q0c.w, kc.w, da); db = fmaf(q1c.w, kc.w, db);
        da = fmaf(q0d.x, kd.x, da); db = fmaf(q1d.x, kd.x, db);
        da = fmaf(q0d.y, kd.y, da); db = fmaf(q1d.y, kd.y, db);
        da = fmaf(q0d.z, kd.z, da); db = fmaf(q1d.z, kd.z, db);
        da = fmaf(q0d.w, kd.w, da); db = fmaf(q1d.w, kd.w, db);
        sum0 += __builtin_amdgcn_exp2f(fmaf(da, C_L2E, -C_L2E));
        sum1 += __builtin_amdgcn_exp2f(fmaf(db, C_L2E, -C_L2E));
    }
    partial[(size_t)chunk * 16384 + b * SDIM + s0] = sum0;
    partial[(size_t)chunk * 16384 + b * SDIM + s1] = sum1;

    if (chunk == 0) {   // diagonal dots, once per (b, s)
        diag[b * SDIM + s0] = dot16(q0a, q0b, q0c, q0d, fk + (size_t)s0 * 16);
        diag[b * SDIM + s1] = dot16(q1a, q1b, q1c, q1d, fk + (size_t)s1 * 16);
    }
}

// ---------------- Kernel C: finalize loss ----------------
__global__ __launch_bounds__(256) void loss_kernel(
    const float* __restrict__ partial, const float* __restrict__ diag,
    float* __restrict__ out)
{
    const int idx = blockIdx.x * 256 + threadIdx.x;  // 0..16383 = b*S+s
    float tot = 0.0f;
    #pragma unroll
    for (int c = 0; c < NCHUNK; ++c) tot += partial[(size_t)c * 16384 + idx];
    float loss = INV_TAU + __logf(tot) - diag[idx] * INV_TAU;

    loss += __shfl_xor(loss, 32, 64);
    loss += __shfl_xor(loss, 16, 64);
    loss += __shfl_xor(loss, 8, 64);
    loss += __shfl_xor(loss, 4, 64);
    loss += __shfl_xor(loss, 2, 64);
    loss += __shfl_xor(loss, 1, 64);

    __shared__ float wsum[4];
    const int lane = threadIdx.x & 63, w = threadIdx.x >> 6;
    if (lane == 0) wsum[w] = loss;
    __syncthreads();
    if (threadIdx.x == 0) {
        float blk = wsum[0] + wsum[1] + wsum[2] + wsum[3];
        atomicAdd(out, blk * (1.0f / 16384.0f));
    }
}

extern "C" void kernel_launch(void* const* d_in, const int* in_sizes, int n_in,
                              void* d_out, int out_size, void* d_ws, size_t ws_size,
                              hipStream_t stream) {
    const float* f_q   = (const float*)d_in[0];
    const float* f_k   = (const float*)d_in[1];
    const float* W0    = (const float*)d_in[2];
    const float* b0    = (const float*)d_in[3];
    const float* W1    = (const float*)d_in[4];
    const float* b1    = (const float*)d_in[5];
    const int*   c_ids = (const int*)d_in[6];
    const int*   n_ids = (const int*)d_in[7];

    float* ws      = (float*)d_ws;
    float* Fq      = ws;                  // B*S*16 = 262144 floats
    float* Fk      = Fq + 262144;         // 262144 floats
    float* partial = Fk + 262144;         // NCHUNK*B*S = 1048576 floats
    float* diag    = partial + 1048576;   // B*S = 16384 floats
    float* out     = (float*)d_out;

    hipMemsetAsync(d_out, 0, sizeof(float), stream);
    feat_kernel<<<1024, 256, 0, stream>>>(f_q, f_k, W0, b0, W1, b1, c_ids, n_ids, Fq, Fk);
    gram_kernel<<<dim3(4, NCHUNK, 8), 256, 0, stream>>>(Fq, Fk, partial, diag);
    loss_kernel<<<64, 256, 0, stream>>>(partial, diag, out);
}

// Round 6
// 286.490 us; speedup vs baseline: 1.0392x; 1.0392x over previous
//
#include <hip/hip_runtime.h>
#include <math.h>

#define HWSZ 65536
#define WIMG 256
#define SDIM 2048
#define NCHUNK 32
#define CHUNKSZ 64
#define INV_TAU 14.285714285714286f
#define C_L2E 20.609929155482418f   // (1/tau) * log2(e)
#define EPSN 1e-7f

// 4-float vector with 4-byte alignment: compiler emits widest legal load for
// the actual alignment (neighbor spans start at arbitrary pixel index).
typedef float f4u __attribute__((ext_vector_type(4), aligned(4)));

// ---------------- Kernel A: gather-diff -> MLP -> L2 normalize ----------------
// One wave per (which, b, center). The 8 neighbors + center are three 3-float
// row spans: top = cid-W-1..+1, mid = cid-1..+1 (center = mid.y), bot = cid+W-1..+1.
__global__ __launch_bounds__(256) void feat_kernel(
    const float* __restrict__ f_q, const float* __restrict__ f_k,
    const float* __restrict__ W0, const float* __restrict__ b0,
    const float* __restrict__ W1, const float* __restrict__ b1,
    const int* __restrict__ c_ids, const int* __restrict__ n_ids,
    float* __restrict__ Fq, float* __restrict__ Fk)
{
    __shared__ float sd[4][64][12];
    __shared__ float sh[4][8][68];
    const int w    = threadIdx.x >> 6;
    const int lane = threadIdx.x & 63;
    const int row  = blockIdx.x * 4 + w;       // 0..4095
    const int which = row >> 11;               // 0 = f_q, 1 = f_k
    const int r = row & 2047;
    const int b = r >> 8;
    const int cidx = r & 255;                  // center index

    const float* feat = which ? f_k : f_q;
    const int cid = c_ids[cidx];               // wave-uniform
    const float* base = feat + ((size_t)(b * 64 + lane)) * HWSZ;  // lane = channel
    const f4u top = *(const f4u*)(base + cid - WIMG - 1);
    const f4u mid = *(const f4u*)(base + cid - 1);
    const f4u bot = *(const f4u*)(base + cid + WIMG - 1);
    const float cval = mid.y;
    float4 d0, d1;
    d0.x = cval - top.x;   // offset -(W+1)
    d0.y = cval - top.y;   // offset -W
    d0.z = cval - top.z;   // offset -(W-1)
    d0.w = cval - mid.x;   // offset -1
    d1.x = cval - mid.z;   // offset +1
    d1.y = cval - bot.x;   // offset W-1
    d1.z = cval - bot.y;   // offset W
    d1.w = cval - bot.z;   // offset W+1
    *(float4*)&sd[w][lane][0] = d0;
    *(float4*)&sd[w][lane][4] = d1;
    __syncthreads();

    // layer 1: lane = j; 8 samples per wave, broadcast b128 reads of d
    float acc[8];
    const float bias0 = b0[lane];
    #pragma unroll
    for (int k = 0; k < 8; ++k) acc[k] = bias0;
    #pragma unroll 8
    for (int c = 0; c < 64; ++c) {
        const float w0 = W0[c * 64 + lane];
        const float4 a = *(const float4*)&sd[w][c][0];
        const float4 e = *(const float4*)&sd[w][c][4];
        acc[0] = fmaf(a.x, w0, acc[0]);
        acc[1] = fmaf(a.y, w0, acc[1]);
        acc[2] = fmaf(a.z, w0, acc[2]);
        acc[3] = fmaf(a.w, w0, acc[3]);
        acc[4] = fmaf(e.x, w0, acc[4]);
        acc[5] = fmaf(e.y, w0, acc[5]);
        acc[6] = fmaf(e.z, w0, acc[6]);
        acc[7] = fmaf(e.w, w0, acc[7]);
    }
    #pragma unroll
    for (int k = 0; k < 8; ++k) sh[w][k][lane] = fmaxf(acc[k], 0.0f);
    __syncthreads();

    // layer 2: lane = k0*16 + i; two passes; float4 broadcast reads of h
    const int i  = lane & 15;
    const int k0 = lane >> 4;
    float* F = which ? Fk : Fq;
    #pragma unroll
    for (int p = 0; p < 2; ++p) {
        const int k = p * 4 + k0;
        float o = b1[i];
        #pragma unroll
        for (int j4 = 0; j4 < 16; ++j4) {
            const float4 h4 = *(const float4*)&sh[w][k][j4 * 4];
            o = fmaf(h4.x, W1[(j4 * 4 + 0) * 16 + i], o);
            o = fmaf(h4.y, W1[(j4 * 4 + 1) * 16 + i], o);
            o = fmaf(h4.z, W1[(j4 * 4 + 2) * 16 + i], o);
            o = fmaf(h4.w, W1[(j4 * 4 + 3) * 16 + i], o);
        }
        float s2 = o * o;
        s2 += __shfl_xor(s2, 1, 16);
        s2 += __shfl_xor(s2, 2, 16);
        s2 += __shfl_xor(s2, 4, 16);
        s2 += __shfl_xor(s2, 8, 16);
        const float val = o / (sqrtf(s2) + EPSN);
        const int s = cidx + 256 * k;
        F[((size_t)(b * SDIM + s)) * 16 + i] = val;
    }
}

// ---------------- Kernel B: Gram row partial logsumexp sums ----------------
// grid = (S/256, NCHUNK, B) = 2048 blocks -> 8 waves/SIMD. Branch-free body;
// exp(x/tau - 1/tau) computed as exp2(fma(x, C, -C)) -> single v_exp_f32.
__global__ __launch_bounds__(256) void gram_kernel(
    const float* __restrict__ Fq, const float* __restrict__ Fk,
    float* __restrict__ partial)
{
    const int s     = blockIdx.x * 256 + threadIdx.x;
    const int chunk = blockIdx.y;
    const int b     = blockIdx.z;

    const float4* q4 = (const float4*)(Fq + ((size_t)(b * SDIM + s)) * 16);
    const float4 qa = q4[0], qb = q4[1], qc = q4[2], qd = q4[3];
    const float* fk = Fk + (size_t)b * SDIM * 16;

    float sum0 = 0.0f, sum1 = 0.0f;
    const int t0 = chunk * CHUNKSZ;
    for (int t = t0; t < t0 + CHUNKSZ; t += 2) {
        const float4* ka4 = (const float4*)(fk + (size_t)t * 16);
        const float4* kb4 = (const float4*)(fk + (size_t)(t + 1) * 16);
        const float4 k0a = ka4[0], k0b = ka4[1], k0c = ka4[2], k0d = ka4[3];
        const float4 k1a = kb4[0], k1b = kb4[1], k1c = kb4[2], k1d = kb4[3];
        float da = qa.x * k0a.x, db = qa.x * k1a.x;
        da = fmaf(qa.y, k0a.y, da); db = fmaf(qa.y, k1a.y, db);
        da = fmaf(qa.z, k0a.z, da); db = fmaf(qa.z, k1a.z, db);
        da = fmaf(qa.w, k0a.w, da); db = fmaf(qa.w, k1a.w, db);
        da = fmaf(qb.x, k0b.x, da); db = fmaf(qb.x, k1b.x, db);
        da = fmaf(qb.y, k0b.y, da); db = fmaf(qb.y, k1b.y, db);
        da = fmaf(qb.z, k0b.z, da); db = fmaf(qb.z, k1b.z, db);
        da = fmaf(qb.w, k0b.w, da); db = fmaf(qb.w, k1b.w, db);
        da = fmaf(qc.x, k0c.x, da); db = fmaf(qc.x, k1c.x, db);
        da = fmaf(qc.y, k0c.y, da); db = fmaf(qc.y, k1c.y, db);
        da = fmaf(qc.z, k0c.z, da); db = fmaf(qc.z, k1c.z, db);
        da = fmaf(qc.w, k0c.w, da); db = fmaf(qc.w, k1c.w, db);
        da = fmaf(qd.x, k0d.x, da); db = fmaf(qd.x, k1d.x, db);
        da = fmaf(qd.y, k0d.y, da); db = fmaf(qd.y, k1d.y, db);
        da = fmaf(qd.z, k0d.z, da); db = fmaf(qd.z, k1d.z, db);
        da = fmaf(qd.w, k0d.w, da); db = fmaf(qd.w, k1d.w, db);
        sum0 += __builtin_amdgcn_exp2f(fmaf(da, C_L2E, -C_L2E));
        sum1 += __builtin_amdgcn_exp2f(fmaf(db, C_L2E, -C_L2E));
    }
    partial[(size_t)chunk * 16384 + b * SDIM + s] = sum0 + sum1;
}

// ---------------- Kernel C: finalize loss (diag computed inline) ----------------
__global__ __launch_bounds__(256) void loss_kernel(
    const float* __restrict__ partial,
    const float* __restrict__ Fq, const float* __restrict__ Fk,
    float* __restrict__ out)
{
    const int idx = blockIdx.x * 256 + threadIdx.x;  // 0..16383 = b*S+s
    float tot = 0.0f;
    #pragma unroll
    for (int c = 0; c < NCHUNK; ++c) tot += partial[(size_t)c * 16384 + idx];

    // diagonal dot q_s . k_s
    const float4* q4 = (const float4*)(Fq + (size_t)idx * 16);
    const float4* k4 = (const float4*)(Fk + (size_t)idx * 16);
    const float4 qa = q4[0], qb = q4[1], qc = q4[2], qd = q4[3];
    const float4 ka = k4[0], kb = k4[1], kc = k4[2], kd = k4[3];
    float dot = qa.x * ka.x;
    dot = fmaf(qa.y, ka.y, dot); dot = fmaf(qa.z, ka.z, dot); dot = fmaf(qa.w, ka.w, dot);
    dot = fmaf(qb.x, kb.x, dot); dot = fmaf(qb.y, kb.y, dot); dot = fmaf(qb.z, kb.z, dot); dot = fmaf(qb.w, kb.w, dot);
    dot = fmaf(qc.x, kc.x, dot); dot = fmaf(qc.y, kc.y, dot); dot = fmaf(qc.z, kc.z, dot); dot = fmaf(qc.w, kc.w, dot);
    dot = fmaf(qd.x, kd.x, dot); dot = fmaf(qd.y, kd.y, dot); dot = fmaf(qd.z, kd.z, dot); dot = fmaf(qd.w, kd.w, dot);

    float loss = INV_TAU + __logf(tot) - dot * INV_TAU;

    loss += __shfl_xor(loss, 32, 64);
    loss += __shfl_xor(loss, 16, 64);
    loss += __shfl_xor(loss, 8, 64);
    loss += __shfl_xor(loss, 4, 64);
    loss += __shfl_xor(loss, 2, 64);
    loss += __shfl_xor(loss, 1, 64);

    __shared__ float wsum[4];
    const int lane = threadIdx.x & 63, w = threadIdx.x >> 6;
    if (lane == 0) wsum[w] = loss;
    __syncthreads();
    if (threadIdx.x == 0) {
        float blk = wsum[0] + wsum[1] + wsum[2] + wsum[3];
        atomicAdd(out, blk * (1.0f / 16384.0f));
    }
}

extern "C" void kernel_launch(void* const* d_in, const int* in_sizes, int n_in,
                              void* d_out, int out_size, void* d_ws, size_t ws_size,
                              hipStream_t stream) {
    const float* f_q   = (const float*)d_in[0];
    const float* f_k   = (const float*)d_in[1];
    const float* W0    = (const float*)d_in[2];
    const float* b0    = (const float*)d_in[3];
    const float* W1    = (const float*)d_in[4];
    const float* b1    = (const float*)d_in[5];
    const int*   c_ids = (const int*)d_in[6];
    const int*   n_ids = (const int*)d_in[7];

    float* ws      = (float*)d_ws;
    float* Fq      = ws;                  // B*S*16 = 262144 floats
    float* Fk      = Fq + 262144;         // 262144 floats
    float* partial = Fk + 262144;         // NCHUNK*B*S = 524288 floats
    float* out     = (float*)d_out;

    hipMemsetAsync(d_out, 0, sizeof(float), stream);
    feat_kernel<<<1024, 256, 0, stream>>>(f_q, f_k, W0, b0, W1, b1, c_ids, n_ids, Fq, Fk);
    gram_kernel<<<dim3(SDIM / 256, NCHUNK, 8), 256, 0, stream>>>(Fq, Fk, partial);
    loss_kernel<<<64, 256, 0, stream>>>(partial, Fq, Fk, out);
}